// Round 8
// baseline (176.220 us; speedup 1.0000x reference)
//
#include <hip/hip_runtime.h>

#define N_NODES 100000
#define N_EDGES 1280000
#define DIM 64
#define NBINS 391          // nodes binned by dst>>8 (256 nodes/bin)
#define CAP 3712           // bin mean 3274, sd 57 -> +7.6 sd
#define EPB 4096           // edges per fill block
#define NFB 313            // ceil(N_EDGES / EPB)
#define CONVB 512          // conv blocks appended after the NFB fill blocks
#define WSCALE (1.0f / 32767.0f)

__device__ __forceinline__ unsigned bf16_rne(float x) {
    unsigned u = __float_as_uint(x);
    return (u + 0x7fffu + ((u >> 16) & 1u)) >> 16;
}
__device__ __forceinline__ float rl_f(float v, int l) {
    return __int_as_float(__builtin_amdgcn_readlane(__float_as_int(v), l));
}
__device__ __forceinline__ float bf_lo(unsigned q) { return __uint_as_float(q << 16); }
__device__ __forceinline__ float bf_hi(unsigned q) { return __uint_as_float(q & 0xffff0000u); }

// ---- fused: blocks [0,NFB) bucket edges; blocks [NFB,NFB+CONVB) compute fW=bf16(feat@W).
// __launch_bounds__(256,2): VGPR cap 256 so the conv half's wcol[64] stays in
// registers (R7 showed VGPR_Count=40 -> wcol spilled; conv was ~35us, not ~8).
__global__ __launch_bounds__(256, 2) void k_fill_conv(
    const int* __restrict__ src, const float* __restrict__ w,
    const int* __restrict__ dst, int* __restrict__ cursor,
    uint2* __restrict__ binned,
    const float* __restrict__ feat, const float* __restrict__ W,
    unsigned short* __restrict__ fW) {
    __shared__ int h[NBINS];
    __shared__ int base_[NBINS];
    int t = threadIdx.x;

    if (blockIdx.x < NFB) {
        // ---------------- fill half ----------------
        for (int i = t; i < NBINS; i += 256) h[i] = 0;
        __syncthreads();
        int eb = blockIdx.x * EPB;
        int d[16], sv[16];
        unsigned wq[16];
        #pragma unroll
        for (int j = 0; j < 16; ++j) {
            int e = eb + j * 256 + t;
            if (e < N_EDGES) {
                d[j] = dst[e];
                sv[j] = src[e];
                wq[j] = (unsigned)(w[e] * 32767.0f + 0.5f);
                atomicAdd(&h[d[j] >> 8], 1);
            } else d[j] = -1;
        }
        __syncthreads();
        for (int i = t; i < NBINS; i += 256) {
            int c = h[i];
            base_[i] = c ? atomicAdd(&cursor[i], c) : 0;
            h[i] = 0;   // reuse as local cursor
        }
        __syncthreads();
        #pragma unroll
        for (int j = 0; j < 16; ++j) {
            if (d[j] >= 0) {
                int bin = d[j] >> 8;
                int pos = base_[bin] + atomicAdd(&h[bin], 1);
                binned[bin * CAP + pos] =
                    make_uint2((unsigned)sv[j] | ((unsigned)(d[j] & 255) << 17), wq[j]);
            }
        }
    } else {
        // ---------------- convgemm half: fW = bf16(feat @ W) ----------------
        int lane = t & 63;
        float wcol[DIM];
        #pragma unroll
        for (int k = 0; k < DIM; ++k) wcol[k] = W[k * DIM + lane];
        int wave = ((blockIdx.x - NFB) * 256 + t) >> 6;
        int nw = CONVB * 4;
        for (int n0 = wave; n0 < N_NODES; n0 += 2 * nw) {
            int n1 = n0 + nw;
            float ha = feat[n0 * DIM + lane];
            float hb = (n1 < N_NODES) ? feat[n1 * DIM + lane] : 0.f;
            float a0 = 0, a1 = 0, a2 = 0, a3 = 0, b0 = 0, b1 = 0, b2 = 0, b3 = 0;
            #pragma unroll
            for (int k = 0; k < DIM; k += 4) {
                a0 = fmaf(rl_f(ha, k + 0), wcol[k + 0], a0);
                a1 = fmaf(rl_f(ha, k + 1), wcol[k + 1], a1);
                a2 = fmaf(rl_f(ha, k + 2), wcol[k + 2], a2);
                a3 = fmaf(rl_f(ha, k + 3), wcol[k + 3], a3);
                b0 = fmaf(rl_f(hb, k + 0), wcol[k + 0], b0);
                b1 = fmaf(rl_f(hb, k + 1), wcol[k + 1], b1);
                b2 = fmaf(rl_f(hb, k + 2), wcol[k + 2], b2);
                b3 = fmaf(rl_f(hb, k + 3), wcol[k + 3], b3);
            }
            fW[n0 * DIM + lane] = (unsigned short)bf16_rne((a0 + a1) + (a2 + a3));
            if (n1 < N_NODES)
                fW[n1 * DIM + lane] = (unsigned short)bf16_rne((b0 + b1) + (b2 + b3));
        }
    }
}

// ---- per-bin in-LDS counting sort -> packed CSR (src17|w15), offs, cnt ----
__global__ __launch_bounds__(256) void k_sortbin(const uint2* __restrict__ binned,
                                                 const int* __restrict__ cursor,
                                                 unsigned* __restrict__ csrp,
                                                 int* __restrict__ offs,
                                                 int* __restrict__ cnt) {
    __shared__ int h[256];
    __shared__ int excl[256];
    __shared__ unsigned stage[CAP];
    int b = blockIdx.x, t = threadIdx.x;
    int total = cursor[b];
    int segbase = b * CAP;
    h[t] = 0;
    __syncthreads();
    for (int i = t; i < total; i += 256)
        atomicAdd(&h[(binned[segbase + i].x >> 17) & 255], 1);
    __syncthreads();
    int v = h[t];
    excl[t] = v;
    __syncthreads();
    for (int off = 1; off < 256; off <<= 1) {
        int add = (t >= off) ? excl[t - off] : 0;
        __syncthreads();
        excl[t] += add;
        __syncthreads();
    }
    int ex = excl[t] - v;
    excl[t] = ex;
    int node = (b << 8) + t;
    if (node < N_NODES) { cnt[node] = v; offs[node] = segbase + ex; }
    h[t] = 0;   // reuse as per-node cursor
    __syncthreads();
    for (int i = t; i < total; i += 256) {
        uint2 e = binned[segbase + i];
        int o = (e.x >> 17) & 255;
        int pos = excl[o] + atomicAdd(&h[o], 1);
        if (pos < CAP) stage[pos] = (e.x & 0x1ffffu) | (e.y << 17);
    }
    __syncthreads();
    for (int i = t; i < total; i += 256)
        csrp[segbase + i] = stage[i];   // coalesced flush
}

// ---- gather fW rows, normalize, store. Two adjacent nodes per wave iteration:
// their CSR segments are contiguous, and interleaving doubles loads in flight. ----
__global__ __launch_bounds__(256) void k_gather(const uint4* __restrict__ fW4,
                                                const unsigned* __restrict__ csrp,
                                                const int* __restrict__ offs,
                                                const int* __restrict__ cnt,
                                                float* __restrict__ out) {
    int lane = threadIdx.x & 63;
    int g = lane >> 3, s = lane & 7;
    int wave = (blockIdx.x * 256 + threadIdx.x) >> 6;
    int nw = gridDim.x * 4;

    for (int n0 = wave * 2; n0 < N_NODES; n0 += nw * 2) {
        int n1 = n0 + 1;   // N_NODES even -> n1 always valid
        int s0 = offs[n0], c0 = cnt[n0];
        int s1 = offs[n1], c1 = cnt[n1];
        int e0 = s0 + c0, e1 = s1 + c1;
        int rounds = (c0 > c1) ? c0 : c1;
        float a[8] = {0, 0, 0, 0, 0, 0, 0, 0};
        float b[8] = {0, 0, 0, 0, 0, 0, 0, 0};
        for (int i = 0; i < rounds; i += 16) {
            int i00 = s0 + i + g,      i01 = s0 + i + 8 + g;
            int i10 = s1 + i + g,      i11 = s1 + i + 8 + g;
            unsigned p00 = csrp[(i00 < e0) ? i00 : s0];
            unsigned p01 = csrp[(i01 < e0) ? i01 : s0];
            unsigned p10 = csrp[(i10 < e1) ? i10 : s1];
            unsigned p11 = csrp[(i11 < e1) ? i11 : s1];
            float w00 = (i00 < e0) ? (float)(p00 >> 17) * WSCALE : 0.f;
            float w01 = (i01 < e0) ? (float)(p01 >> 17) * WSCALE : 0.f;
            float w10 = (i10 < e1) ? (float)(p10 >> 17) * WSCALE : 0.f;
            float w11 = (i11 < e1) ? (float)(p11 >> 17) * WSCALE : 0.f;
            uint4 q00 = fW4[((p00 & 0x1ffffu) << 3) + s];
            uint4 q01 = fW4[((p01 & 0x1ffffu) << 3) + s];
            uint4 q10 = fW4[((p10 & 0x1ffffu) << 3) + s];
            uint4 q11 = fW4[((p11 & 0x1ffffu) << 3) + s];
            a[0] = fmaf(bf_lo(q00.x), w00, a[0]); a[1] = fmaf(bf_hi(q00.x), w00, a[1]);
            a[2] = fmaf(bf_lo(q00.y), w00, a[2]); a[3] = fmaf(bf_hi(q00.y), w00, a[3]);
            a[4] = fmaf(bf_lo(q00.z), w00, a[4]); a[5] = fmaf(bf_hi(q00.z), w00, a[5]);
            a[6] = fmaf(bf_lo(q00.w), w00, a[6]); a[7] = fmaf(bf_hi(q00.w), w00, a[7]);
            a[0] = fmaf(bf_lo(q01.x), w01, a[0]); a[1] = fmaf(bf_hi(q01.x), w01, a[1]);
            a[2] = fmaf(bf_lo(q01.y), w01, a[2]); a[3] = fmaf(bf_hi(q01.y), w01, a[3]);
            a[4] = fmaf(bf_lo(q01.z), w01, a[4]); a[5] = fmaf(bf_hi(q01.z), w01, a[5]);
            a[6] = fmaf(bf_lo(q01.w), w01, a[6]); a[7] = fmaf(bf_hi(q01.w), w01, a[7]);
            b[0] = fmaf(bf_lo(q10.x), w10, b[0]); b[1] = fmaf(bf_hi(q10.x), w10, b[1]);
            b[2] = fmaf(bf_lo(q10.y), w10, b[2]); b[3] = fmaf(bf_hi(q10.y), w10, b[3]);
            b[4] = fmaf(bf_lo(q10.z), w10, b[4]); b[5] = fmaf(bf_hi(q10.z), w10, b[5]);
            b[6] = fmaf(bf_lo(q10.w), w10, b[6]); b[7] = fmaf(bf_hi(q10.w), w10, b[7]);
            b[0] = fmaf(bf_lo(q11.x), w11, b[0]); b[1] = fmaf(bf_hi(q11.x), w11, b[1]);
            b[2] = fmaf(bf_lo(q11.y), w11, b[2]); b[3] = fmaf(bf_hi(q11.y), w11, b[3]);
            b[4] = fmaf(bf_lo(q11.z), w11, b[4]); b[5] = fmaf(bf_hi(q11.z), w11, b[5]);
            b[6] = fmaf(bf_lo(q11.w), w11, b[6]); b[7] = fmaf(bf_hi(q11.w), w11, b[7]);
        }
        #pragma unroll
        for (int j = 0; j < 8; ++j) {
            a[j] += __shfl_xor(a[j], 8, 64);
            a[j] += __shfl_xor(a[j], 16, 64);
            a[j] += __shfl_xor(a[j], 32, 64);
            b[j] += __shfl_xor(b[j], 8, 64);
            b[j] += __shfl_xor(b[j], 16, 64);
            b[j] += __shfl_xor(b[j], 32, 64);
        }
        float d0 = 1.0f / fmaxf((float)c0, 1.0f);
        float d1 = 1.0f / fmaxf((float)c1, 1.0f);
        if (g == 0) {   // lanes 0..7 store n0
            float4 o0, o1;
            o0.x = a[0] * d0; o0.y = a[1] * d0; o0.z = a[2] * d0; o0.w = a[3] * d0;
            o1.x = a[4] * d0; o1.y = a[5] * d0; o1.z = a[6] * d0; o1.w = a[7] * d0;
            ((float4*)out)[n0 * 16 + s * 2 + 0] = o0;
            ((float4*)out)[n0 * 16 + s * 2 + 1] = o1;
        } else if (g == 1) {   // lanes 8..15 store n1
            float4 o0, o1;
            o0.x = b[0] * d1; o0.y = b[1] * d1; o0.z = b[2] * d1; o0.w = b[3] * d1;
            o1.x = b[4] * d1; o1.y = b[5] * d1; o1.z = b[6] * d1; o1.w = b[7] * d1;
            ((float4*)out)[n1 * 16 + s * 2 + 0] = o0;
            ((float4*)out)[n1 * 16 + s * 2 + 1] = o1;
        }
    }
}

extern "C" void kernel_launch(void* const* d_in, const int* in_sizes, int n_in,
                              void* d_out, int out_size, void* d_ws, size_t ws_size,
                              hipStream_t stream) {
    const float* feat = (const float*)d_in[0];
    const float* w    = (const float*)d_in[1];
    const float* W    = (const float*)d_in[2];
    const int*   src  = (const int*)d_in[3];
    const int*   dst  = (const int*)d_in[4];
    float* out = (float*)d_out;

    // No aliasing (fill and conv overlap). ~31 MB total, ws is 256 MiB.
    unsigned short* fW = (unsigned short*)d_ws;                  // 12.8 MB, 16B-aligned
    uint2* binned  = (uint2*)(fW + (size_t)N_NODES * DIM);       // NBINS*CAP*8 = 11.6 MB
    unsigned* csrp = (unsigned*)(binned + (size_t)NBINS * CAP);  // 5.8 MB
    int* offs      = (int*)(csrp + (size_t)NBINS * CAP);         // N_NODES
    int* cnt       = offs + N_NODES;                             // N_NODES
    int* cursor    = cnt + N_NODES;                              // NBINS

    hipMemsetAsync(cursor, 0, NBINS * sizeof(int), stream);

    k_fill_conv<<<NFB + CONVB, 256, 0, stream>>>(src, w, dst, cursor, binned,
                                                 feat, W, fW);
    k_sortbin<<<NBINS, 256, 0, stream>>>(binned, cursor, csrp, offs, cnt);
    k_gather<<<2048, 256, 0, stream>>>((const uint4*)fW, csrp, offs, cnt, out);
}

// Round 9
// 156.141 us; speedup vs baseline: 1.1286x; 1.1286x over previous
//
#include <hip/hip_runtime.h>

#define N_NODES 100000
#define N_EDGES 1280000
#define DIM 64
#define NBINS 391          // nodes binned by dst>>8 (256 nodes/bin)
#define CAP 3712           // bin mean 3274, sd 57 -> +7.6 sd
#define EPB 4096           // edges per fill block
#define NFB 313            // ceil(N_EDGES / EPB)
#define CONVB 512          // conv blocks appended after the NFB fill blocks
#define NTILES 1563        // ceil(N_NODES / 64)
#define FPAD 68            // feat tile leading dim (64+4): keeps b128 align, 2-way banks
#define WSCALE (1.0f / 32767.0f)

__device__ __forceinline__ unsigned bf16_rne(float x) {
    unsigned u = __float_as_uint(x);
    return (u + 0x7fffu + ((u >> 16) & 1u)) >> 16;
}
__device__ __forceinline__ float bf_lo(unsigned q) { return __uint_as_float(q << 16); }
__device__ __forceinline__ float bf_hi(unsigned q) { return __uint_as_float(q & 0xffff0000u); }

// ---- fused: blocks [0,NFB) bucket edges; blocks [NFB,NFB+CONVB) compute fW=bf16(feat@W)
// as an LDS-tiled GEMM (R7/R8 showed the register allocator refuses to keep a 64-reg
// W column live -> scratch churn; LDS tiling needs only ~60 VGPRs by design).
__global__ __launch_bounds__(256) void k_fill_conv(
    const int* __restrict__ src, const float* __restrict__ w,
    const int* __restrict__ dst, int* __restrict__ cursor,
    uint2* __restrict__ binned,
    const float* __restrict__ feat, const float* __restrict__ W,
    unsigned short* __restrict__ fW) {
    __shared__ union U {
        struct { int h[NBINS]; int base_[NBINS]; } fill;
        struct { float w[DIM * DIM]; float f[64 * FPAD]; } conv;
        __device__ U() {}
    } sm;
    int t = threadIdx.x;

    if (blockIdx.x < NFB) {
        // ---------------- fill half ----------------
        for (int i = t; i < NBINS; i += 256) sm.fill.h[i] = 0;
        __syncthreads();
        int eb = blockIdx.x * EPB;
        int d[16], sv[16];
        unsigned wq[16];
        #pragma unroll
        for (int j = 0; j < 16; ++j) {
            int e = eb + j * 256 + t;
            if (e < N_EDGES) {
                d[j] = dst[e];
                sv[j] = src[e];
                wq[j] = (unsigned)(w[e] * 32767.0f + 0.5f);
                atomicAdd(&sm.fill.h[d[j] >> 8], 1);
            } else d[j] = -1;
        }
        __syncthreads();
        for (int i = t; i < NBINS; i += 256) {
            int c = sm.fill.h[i];
            sm.fill.base_[i] = c ? atomicAdd(&cursor[i], c) : 0;
            sm.fill.h[i] = 0;   // reuse as local cursor
        }
        __syncthreads();
        #pragma unroll
        for (int j = 0; j < 16; ++j) {
            if (d[j] >= 0) {
                int bin = d[j] >> 8;
                int pos = sm.fill.base_[bin] + atomicAdd(&sm.fill.h[bin], 1);
                binned[bin * CAP + pos] =
                    make_uint2((unsigned)sv[j] | ((unsigned)(d[j] & 255) << 17), wq[j]);
            }
        }
    } else {
        // ---------------- conv half: fW = bf16(feat @ W), LDS-tiled ----------------
        // stage W once (16 KB), coalesced
        #pragma unroll
        for (int i = 0; i < DIM * DIM / 256; ++i)
            sm.conv.w[t + i * 256] = W[t + i * 256];
        const float4* lds_w4 = (const float4*)sm.conv.w;
        float4* lds_f4 = (float4*)sm.conv.f;
        int tx = t & 15, ny = t >> 4;       // thread tile: nodes ny*4..+3, outs tx*4..+3
        int rr = t >> 2, seg = t & 3;       // staging: row rr, 16-float segment seg

        for (int tb = blockIdx.x - NFB; tb < NTILES; tb += CONVB) {
            int nb = tb * 64;
            __syncthreads();   // protect lds_f from previous tile's readers (also fences W stage)
            // stage feat tile (fully coalesced 16B/lane); zero-pad rows past N_NODES
            #pragma unroll
            for (int q = 0; q < 4; ++q) {
                float4 v = (nb + rr < N_NODES)
                           ? ((const float4*)feat)[(size_t)(nb + rr) * 16 + seg * 4 + q]
                           : make_float4(0.f, 0.f, 0.f, 0.f);
                lds_f4[(rr * FPAD + seg * 16 + q * 4) >> 2] = v;
            }
            __syncthreads();
            // compute 4x4 register tile, k blocked by 4 (all LDS reads are b128)
            float acc[4][4];
            #pragma unroll
            for (int i = 0; i < 4; ++i)
                #pragma unroll
                for (int j = 0; j < 4; ++j) acc[i][j] = 0.f;
            for (int k0 = 0; k0 < DIM; k0 += 4) {
                float4 hv[4], wv[4];
                #pragma unroll
                for (int i = 0; i < 4; ++i)
                    hv[i] = lds_f4[((ny * 4 + i) * FPAD + k0) >> 2];
                #pragma unroll
                for (int j = 0; j < 4; ++j)
                    wv[j] = lds_w4[((k0 + j) * DIM + tx * 4) >> 2];
                #pragma unroll
                for (int i = 0; i < 4; ++i) {
                    const float* hp = (const float*)&hv[i];
                    #pragma unroll
                    for (int kk = 0; kk < 4; ++kk) {
                        float hk = hp[kk];
                        acc[i][0] = fmaf(hk, ((const float*)&wv[kk])[0], acc[i][0]);
                        acc[i][1] = fmaf(hk, ((const float*)&wv[kk])[1], acc[i][1]);
                        acc[i][2] = fmaf(hk, ((const float*)&wv[kk])[2], acc[i][2]);
                        acc[i][3] = fmaf(hk, ((const float*)&wv[kk])[3], acc[i][3]);
                    }
                }
            }
            // store bf16 (8 B/lane, coalesced per node row)
            #pragma unroll
            for (int i = 0; i < 4; ++i) {
                int node = nb + ny * 4 + i;
                if (node < N_NODES) {
                    ushort4 o;
                    o.x = (unsigned short)bf16_rne(acc[i][0]);
                    o.y = (unsigned short)bf16_rne(acc[i][1]);
                    o.z = (unsigned short)bf16_rne(acc[i][2]);
                    o.w = (unsigned short)bf16_rne(acc[i][3]);
                    *(ushort4*)(fW + (size_t)node * DIM + tx * 4) = o;
                }
            }
        }
    }
}

// ---- per-bin in-LDS counting sort -> packed CSR (src17|w15), offs, cnt ----
__global__ __launch_bounds__(256) void k_sortbin(const uint2* __restrict__ binned,
                                                 const int* __restrict__ cursor,
                                                 unsigned* __restrict__ csrp,
                                                 int* __restrict__ offs,
                                                 int* __restrict__ cnt) {
    __shared__ int h[256];
    __shared__ int excl[256];
    __shared__ unsigned stage[CAP];
    int b = blockIdx.x, t = threadIdx.x;
    int total = cursor[b];
    int segbase = b * CAP;
    h[t] = 0;
    __syncthreads();
    for (int i = t; i < total; i += 256)
        atomicAdd(&h[(binned[segbase + i].x >> 17) & 255], 1);
    __syncthreads();
    int v = h[t];
    excl[t] = v;
    __syncthreads();
    for (int off = 1; off < 256; off <<= 1) {
        int add = (t >= off) ? excl[t - off] : 0;
        __syncthreads();
        excl[t] += add;
        __syncthreads();
    }
    int ex = excl[t] - v;
    excl[t] = ex;
    int node = (b << 8) + t;
    if (node < N_NODES) { cnt[node] = v; offs[node] = segbase + ex; }
    h[t] = 0;   // reuse as per-node cursor
    __syncthreads();
    for (int i = t; i < total; i += 256) {
        uint2 e = binned[segbase + i];
        int o = (e.x >> 17) & 255;
        int pos = excl[o] + atomicAdd(&h[o], 1);
        if (pos < CAP) stage[pos] = (e.x & 0x1ffffu) | (e.y << 17);
    }
    __syncthreads();
    for (int i = t; i < total; i += 256)
        csrp[segbase + i] = stage[i];   // coalesced flush
}

// ---- gather fW rows per node, normalize, store (R7 form) ----
// wave = node; 8 groups of 8 lanes; lane s covers dims 8s..8s+7 (uint4 = 16B load).
__global__ __launch_bounds__(256) void k_gather(const uint4* __restrict__ fW4,
                                                const unsigned* __restrict__ csrp,
                                                const int* __restrict__ offs,
                                                const int* __restrict__ cnt,
                                                float* __restrict__ out) {
    int lane = threadIdx.x & 63;
    int g = lane >> 3, s = lane & 7;
    int wave = (blockIdx.x * 256 + threadIdx.x) >> 6;
    int nw = gridDim.x * 4;

    for (int node = wave; node < N_NODES; node += nw) {
        int start = offs[node];
        int c = cnt[node];
        int end = start + c;
        float a[8] = {0, 0, 0, 0, 0, 0, 0, 0};
        for (int i = start; i < end; i += 16) {
            int i0 = i + g, i1 = i + 8 + g;
            unsigned p0 = csrp[(i0 < end) ? i0 : start];
            unsigned p1 = csrp[(i1 < end) ? i1 : start];
            float w0 = (i0 < end) ? (float)(p0 >> 17) * WSCALE : 0.f;
            float w1 = (i1 < end) ? (float)(p1 >> 17) * WSCALE : 0.f;
            uint4 q0 = fW4[((p0 & 0x1ffffu) << 3) + s];
            uint4 q1 = fW4[((p1 & 0x1ffffu) << 3) + s];
            a[0] = fmaf(bf_lo(q0.x), w0, a[0]); a[1] = fmaf(bf_hi(q0.x), w0, a[1]);
            a[2] = fmaf(bf_lo(q0.y), w0, a[2]); a[3] = fmaf(bf_hi(q0.y), w0, a[3]);
            a[4] = fmaf(bf_lo(q0.z), w0, a[4]); a[5] = fmaf(bf_hi(q0.z), w0, a[5]);
            a[6] = fmaf(bf_lo(q0.w), w0, a[6]); a[7] = fmaf(bf_hi(q0.w), w0, a[7]);
            a[0] = fmaf(bf_lo(q1.x), w1, a[0]); a[1] = fmaf(bf_hi(q1.x), w1, a[1]);
            a[2] = fmaf(bf_lo(q1.y), w1, a[2]); a[3] = fmaf(bf_hi(q1.y), w1, a[3]);
            a[4] = fmaf(bf_lo(q1.z), w1, a[4]); a[5] = fmaf(bf_hi(q1.z), w1, a[5]);
            a[6] = fmaf(bf_lo(q1.w), w1, a[6]); a[7] = fmaf(bf_hi(q1.w), w1, a[7]);
        }
        #pragma unroll
        for (int j = 0; j < 8; ++j) {
            a[j] += __shfl_xor(a[j], 8, 64);
            a[j] += __shfl_xor(a[j], 16, 64);
            a[j] += __shfl_xor(a[j], 32, 64);
        }
        float dinv = 1.0f / fmaxf((float)c, 1.0f);
        if (g == 0) {   // lanes 0..7: lane s holds dims 8s..8s+7
            float4 o0, o1;
            o0.x = a[0] * dinv; o0.y = a[1] * dinv; o0.z = a[2] * dinv; o0.w = a[3] * dinv;
            o1.x = a[4] * dinv; o1.y = a[5] * dinv; o1.z = a[6] * dinv; o1.w = a[7] * dinv;
            ((float4*)out)[node * 16 + s * 2 + 0] = o0;
            ((float4*)out)[node * 16 + s * 2 + 1] = o1;
        }
    }
}

extern "C" void kernel_launch(void* const* d_in, const int* in_sizes, int n_in,
                              void* d_out, int out_size, void* d_ws, size_t ws_size,
                              hipStream_t stream) {
    const float* feat = (const float*)d_in[0];
    const float* w    = (const float*)d_in[1];
    const float* W    = (const float*)d_in[2];
    const int*   src  = (const int*)d_in[3];
    const int*   dst  = (const int*)d_in[4];
    float* out = (float*)d_out;

    // No aliasing (fill and conv overlap). ~31 MB total, ws is 256 MiB.
    unsigned short* fW = (unsigned short*)d_ws;                  // 12.8 MB, 16B-aligned
    uint2* binned  = (uint2*)(fW + (size_t)N_NODES * DIM);       // NBINS*CAP*8 = 11.6 MB
    unsigned* csrp = (unsigned*)(binned + (size_t)NBINS * CAP);  // 5.8 MB
    int* offs      = (int*)(csrp + (size_t)NBINS * CAP);         // N_NODES
    int* cnt       = offs + N_NODES;                             // N_NODES
    int* cursor    = cnt + N_NODES;                              // NBINS

    hipMemsetAsync(cursor, 0, NBINS * sizeof(int), stream);

    k_fill_conv<<<NFB + CONVB, 256, 0, stream>>>(src, w, dst, cursor, binned,
                                                 feat, W, fW);
    k_sortbin<<<NBINS, 256, 0, stream>>>(binned, cursor, csrp, offs, cnt);
    k_gather<<<4096, 256, 0, stream>>>((const uint4*)fW, csrp, offs, cnt, out);
}